// Round 7
// baseline (289.034 us; speedup 1.0000x reference)
//
#include <hip/hip_runtime.h>
#include <hip/hip_bf16.h>
#include <math.h>

// B=32, S=2048, D=1024, H=8, D_HEAD=32, D_HEAD_OUT=128, M=65536
#define S_  2048
#define D_  1024

typedef __attribute__((ext_vector_type(8))) short short8;
typedef __attribute__((ext_vector_type(4))) float f32x4;

static __device__ __forceinline__ short f2bf(float x) {
    return __builtin_bit_cast(short, __float2bfloat16(x));   // HW v_cvt, RTNE
}
static __device__ __forceinline__ float bf2f(unsigned short s) {
    unsigned int u = ((unsigned int)s) << 16;
    return __builtin_bit_cast(float, u);
}

__device__ __forceinline__ void gl_lds16(const void* g, void* l) {
    __builtin_amdgcn_global_load_lds(
        (const __attribute__((address_space(1))) unsigned int*)g,
        (__attribute__((address_space(3))) unsigned int*)l, 16, 0, 0);
}

// ---------------------------------------------------------------------------
// Pack w1 (fp32 [8][1024][32]) -> MFMA B-frag order bf16:
//   w1p[((ks*16+cf)*64+lane)*8+r]; col=cf*16+(lane&15) (=h*32+e),
//   k=ks*32+(lane>>4)*8+r (=d)
__global__ void prep_w1(const float* __restrict__ w1, short* __restrict__ w1p) {
    int tid = blockIdx.x * 256 + threadIdx.x;   // 32768 threads
    int lane = tid & 63;
    int fragid = tid >> 6;
    int cf = fragid & 15, ks = fragid >> 4;
    int col = cf * 16 + (lane & 15);
    int h = col >> 5, e = col & 31;
    int d0 = ks * 32 + (lane >> 4) * 8;
    short8 v;
#pragma unroll
    for (int r = 0; r < 8; ++r)
        v[r] = f2bf(w1[((size_t)h * D_ + (d0 + r)) * 32 + e]);
    *(short8*)(w1p + (size_t)tid * 8) = v;
}

// Pack w2 (fp32 [8][32][128]) -> B-frag order bf16:
//   w2p[((h*8+cf2)*64+lane)*8+r]; col=o=cf2*16+(lane&15), k=e=(lane>>4)*8+r
__global__ void prep_w2(const float* __restrict__ w2, short* __restrict__ w2p) {
    int tid = blockIdx.x * 256 + threadIdx.x;   // 4096 threads
    int lane = tid & 63;
    int fragid = tid >> 6;
    int cf2 = fragid & 7, h = fragid >> 3;
    int o = cf2 * 16 + (lane & 15);
    int e0 = (lane >> 4) * 8;
    short8 v;
#pragma unroll
    for (int r = 0; r < 8; ++r)
        v[r] = f2bf(w2[((size_t)h * 32 + (e0 + r)) * 128 + o]);
    *(short8*)(w2p + (size_t)tid * 8) = v;
}

// ---------------------------------------------------------------------------
// gemm1: hact[m][0..256) = gelu(feat @ w1 + b1), bf16 row-major.
// BM=256 (full-N block): grid 256 x 512 thr (8 waves, 2x4). Wave (wr,wcq)
// owns rows wr*128+[0,128) x cols wcq*64+[0,64); acc 8x4 f32x4 = 128 VGPR.
// Issued vmem: A 256 MB (once) + B restage 128 MB + hact 32 MB.
// A is reg-staged global->cvt->LDS in MFMA-frag order (lane-contiguous 16B
// ds_write/ds_read: conflict-free). B staged via global_load_lds (frag-order
// w1p, linear dest). Simple 2-buffer, one __syncthreads per kstep (R4-proven).
// __launch_bounds__(512,2): 256-VGPR cap >= ~215 live; no spills.
__global__ __launch_bounds__(512, 2) void gemm1(
        const float* __restrict__ feat,
        const short* __restrict__ w1p,
        const float* __restrict__ b1,
        short* __restrict__ hact)
{
    __shared__ __align__(16) char lds[65536];
    short* Abuf = (short*)lds;                 // [2][8192] shorts (2x16KB)
    short* Bbuf = (short*)(lds + 32768);       // [2][8192] shorts
    short* hstage = (short*)lds;               // [64][264] bf16 (epilogue reuse)

    const int tid = threadIdx.x;               // 0..511
    const int wv = tid >> 6;                   // 0..7
    const int lane = tid & 63;
    const int lr = lane & 15;
    const int lg = lane >> 4;
    const int wr = wv >> 2;                    // 0..1
    const int wcq = wv & 3;                    // 0..3
    const size_t m0 = (size_t)blockIdx.x * 256;

    // A staging: 1024 frag-lane-slots of 16B per kstep; thread owns q0,q1.
    // slot q: rf=q>>6, lane_q=q&63; row=rf*16+(lane_q&15); kseg=(lane_q>>4).
    const int q0 = tid, q1 = tid + 512;
    const int row0 = ((q0 >> 6) << 4) + (q0 & 15), kg0 = (q0 >> 4) & 3;
    const int row1 = ((q1 >> 6) << 4) + (q1 & 15), kg1 = (q1 >> 4) & 3;
    const float* gA0 = feat + (m0 + row0) * D_ + kg0 * 8;
    const float* gA1 = feat + (m0 + row1) * D_ + kg1 * 8;

    const f32x4 vzero = {0.f, 0.f, 0.f, 0.f};
    f32x4 acc[8][4];
#pragma unroll
    for (int i = 0; i < 8; ++i)
#pragma unroll
        for (int j = 0; j < 4; ++j) acc[i][j] = vzero;

    f32x4 g0, g1, g2, g3;                      // named A prefetch regs
    auto loadAg = [&](int ks_) {
        const float* p = gA0 + ks_ * 32;
        g0 = *(const f32x4*)p; g1 = *(const f32x4*)(p + 4);
        const float* p2 = gA1 + ks_ * 32;
        g2 = *(const f32x4*)p2; g3 = *(const f32x4*)(p2 + 4);
    };
    auto writeA = [&](int buf_) {
        short8 v;
        v[0] = f2bf(g0.x); v[1] = f2bf(g0.y); v[2] = f2bf(g0.z); v[3] = f2bf(g0.w);
        v[4] = f2bf(g1.x); v[5] = f2bf(g1.y); v[6] = f2bf(g1.z); v[7] = f2bf(g1.w);
        *(short8*)(Abuf + buf_ * 8192 + q0 * 8) = v;
        short8 w;
        w[0] = f2bf(g2.x); w[1] = f2bf(g2.y); w[2] = f2bf(g2.z); w[3] = f2bf(g2.w);
        w[4] = f2bf(g3.x); w[5] = f2bf(g3.y); w[6] = f2bf(g3.z); w[7] = f2bf(g3.w);
        *(short8*)(Abuf + buf_ * 8192 + q1 * 8) = w;
    };
    auto stageB = [&](int buf_, int ks_) {
#pragma unroll
        for (int j = 0; j < 2; ++j)
            gl_lds16(w1p + (size_t)ks_ * 8192 + (size_t)(j * 512 + tid) * 8,
                     Bbuf + buf_ * 8192 + (j * 512 + wv * 64) * 8);
    };

    // prologue: fill buffer 0
    stageB(0, 0);
    loadAg(0);
    writeA(0);
    __syncthreads();

    for (int ks = 0; ks < 32; ++ks) {
        const int buf = ks & 1;
        if (ks < 31) { stageB(buf ^ 1, ks + 1); loadAg(ks + 1); }

        short8 af[8], bf[4];
#pragma unroll
        for (int i = 0; i < 8; ++i)
            af[i] = *(const short8*)(Abuf + buf * 8192 + ((wr * 8 + i) * 64 + lane) * 8);
#pragma unroll
        for (int j = 0; j < 4; ++j)
            bf[j] = *(const short8*)(Bbuf + buf * 8192 + ((wcq * 4 + j) * 64 + lane) * 8);
#pragma unroll
        for (int i = 0; i < 8; ++i)
#pragma unroll
            for (int j = 0; j < 4; ++j)
                acc[i][j] = __builtin_amdgcn_mfma_f32_16x16x32_bf16(af[i], bf[j], acc[i][j], 0, 0, 0);

        if (ks < 31) writeA(buf ^ 1);   // cvt+ds_write after MFMAs cover latency
        __syncthreads();                // stage/writes for buf^1 complete
    }

    // epilogue: +b1, exact-erf gelu; 4 passes of 64 rows via LDS staging.
    // C/D frag layout: col = lane&15, row = (lane>>4)*4 + r.
#pragma unroll
    for (int p = 0; p < 4; ++p) {
        if (wr == (p >> 1)) {
            const int ibase = (p & 1) * 4;
#pragma unroll
            for (int i2 = 0; i2 < 4; ++i2)
#pragma unroll
            for (int j = 0; j < 4; ++j) {
                const int col = wcq * 64 + j * 16 + lr;
                const float bias = b1[col];
#pragma unroll
                for (int r = 0; r < 4; ++r) {
                    const int lrow = i2 * 16 + lg * 4 + r;
                    float x = acc[ibase + i2][j][r] + bias;
                    float g = 0.5f * x * (1.0f + erff(x * 0.70710678118654752f));
                    hstage[lrow * 264 + col] = f2bf(g);
                }
            }
        }
        __syncthreads();
#pragma unroll
        for (int it = 0; it < 4; ++it) {
            const int idx = it * 512 + tid;
            const int row = idx >> 5;
            const int c8 = idx & 31;
            short8 v = *(const short8*)(hstage + row * 264 + c8 * 8);
            *(short8*)(hact + (m0 + (size_t)(p * 64 + row)) * 256 + c8 * 8) = v;
        }
        __syncthreads();
    }
}

// ---------------------------------------------------------------------------
// gemm2w: per 16-row tile: logits = hact @ w2 + b2 ; E = exp(logits) ;
// partials pnum/pden[tile][col] = sum over 16 rows of {feat*E, E}.
// Block 256 thr; wave wv handles heads {2wv, 2wv+1} (logit cols wv*256..+256).
__global__ __launch_bounds__(256) void gemm2w(
        const short* __restrict__ hact,
        const float* __restrict__ feat,
        const short* __restrict__ w2p,
        const float* __restrict__ b2,
        float* __restrict__ pnum,
        float* __restrict__ pden)
{
    __shared__ __align__(16) char lds[41216];
    short* hstage = (short*)lds;                         // [16][256] linear, 8 KB
    unsigned short* Est = (unsigned short*)(lds + 8192); // [16][1032] bf16

    const int tid = threadIdx.x;
    const int wv = tid >> 6;
    const int lane = tid & 63;
    const int lr = lane & 15;
    const int lg = lane >> 4;
    const size_t m0 = (size_t)blockIdx.x * 16;

    // stage 16x256 bf16 hact tile (linear: matches gl_lds16 lane order)
#pragma unroll
    for (int j = 0; j < 2; ++j)
        gl_lds16(hact + m0 * 256 + (size_t)(j * 256 + tid) * 8,
                 hstage + (j * 256 + wv * 64) * 8);

    float bias2[16];
#pragma unroll
    for (int cf = 0; cf < 16; ++cf)
        bias2[cf] = b2[(2 * wv + (cf >> 3)) * 128 + (cf & 7) * 16 + lr];

    __syncthreads();

    // GEMM2 (K=32) + exp -> Est
    short8 ah0 = *(const short8*)(hstage + lr * 256 + (2 * wv + 0) * 32 + lg * 8);
    short8 ah1 = *(const short8*)(hstage + lr * 256 + (2 * wv + 1) * 32 + lg * 8);
    const f32x4 vzero = {0.f, 0.f, 0.f, 0.f};
#pragma unroll
    for (int cf = 0; cf < 16; ++cf) {
        const int h = 2 * wv + (cf >> 3);
        short8 bw = *(const short8*)(w2p + ((size_t)(h * 8 + (cf & 7)) * 64 + lane) * 8);
        f32x4 c = vzero;
        c = __builtin_amdgcn_mfma_f32_16x16x32_bf16((cf < 8) ? ah0 : ah1, bw, c, 0, 0, 0);
        const int colL = wv * 256 + (cf >> 3) * 128 + (cf & 7) * 16 + lr;
#pragma unroll
        for (int r = 0; r < 4; ++r) {
            float e = __expf(c[r] + bias2[cf]);   // logits tiny: no max-sub needed
            Est[(lg * 4 + r) * 1032 + colL] = (unsigned short)f2bf(e);
        }
    }
    __syncthreads();

    // weighting: coalesced f32x4 feat read, E from LDS
    const int c0 = tid * 4;
    f32x4 nacc = vzero, dacc = vzero;
    const float* fb = feat + m0 * D_ + c0;
#pragma unroll
    for (int row = 0; row < 16; ++row) {
        f32x4 fv = *(const f32x4*)(fb + (size_t)row * D_);
        unsigned long long ev = *(const unsigned long long*)(Est + row * 1032 + c0);
        f32x4 e;
        e.x = bf2f((unsigned short)(ev));
        e.y = bf2f((unsigned short)(ev >> 16));
        e.z = bf2f((unsigned short)(ev >> 32));
        e.w = bf2f((unsigned short)(ev >> 48));
        dacc += e;
        nacc += fv * e;
    }
    const size_t pb = (size_t)blockIdx.x * 1024 + c0;
    *(f32x4*)(pnum + pb) = nacc;
    *(f32x4*)(pden + pb) = dacc;
}

// ---------------------------------------------------------------------------
// out[b,d] = sum_{j<128} pnum[(b*128+j)*1024+d] / sum_j pden[...]
__global__ __launch_bounds__(256) void finalize3(
        const float* __restrict__ pnum,
        const float* __restrict__ pden,
        float* __restrict__ out)
{
    const int idx = blockIdx.x * 256 + threadIdx.x;   // 32768 = 32*1024
    const int b = idx >> 10;
    const int d = idx & 1023;
    const size_t base = (size_t)b * 128 * 1024 + d;
    float n = 0.f, dn = 0.f;
    for (int j = 0; j < 128; ++j) {
        n  += pnum[base + (size_t)j * 1024];
        dn += pden[base + (size_t)j * 1024];
    }
    out[idx] = n / dn;
}

// ---------------------------------------------------------------------------
extern "C" void kernel_launch(void* const* d_in, const int* in_sizes, int n_in,
                              void* d_out, int out_size, void* d_ws, size_t ws_size,
                              hipStream_t stream) {
    (void)in_sizes; (void)n_in; (void)out_size; (void)ws_size;
    const float* feat = (const float*)d_in[0];
    const float* w1   = (const float*)d_in[1];
    const float* b1   = (const float*)d_in[2];
    const float* w2   = (const float*)d_in[3];
    const float* b2   = (const float*)d_in[4];
    float* out = (float*)d_out;

    char* ws = (char*)d_ws;
    short* hact = (short*)ws;                              // 32 MiB (65536*256 bf16)
    float* pnum = (float*)(ws + (32ull << 20));            // 16 MiB (4096*1024 f32)
    float* pden = (float*)(ws + (48ull << 20));            // 16 MiB
    short* w1p  = (short*)(ws + (64ull << 20));            // 512 KiB
    short* w2p  = (short*)(ws + (64ull << 20) + (512ull << 10));  // 64 KiB

    prep_w1<<<128, 256, 0, stream>>>(w1, w1p);
    prep_w2<<<16, 256, 0, stream>>>(w2, w2p);
    gemm1<<<256, 512, 0, stream>>>(feat, w1p, b1, hact);
    gemm2w<<<4096, 256, 0, stream>>>(hact, feat, w2p, b2, pnum, pden);
    finalize3<<<128, 256, 0, stream>>>(pnum, pden, out);
}

// Round 8
// 217.218 us; speedup vs baseline: 1.3306x; 1.3306x over previous
//
#include <hip/hip_runtime.h>
#include <hip/hip_bf16.h>
#include <math.h>

// B=32, S=2048, D=1024, H=8, D_HEAD=32, D_HEAD_OUT=128, M=65536
#define S_  2048
#define D_  1024

typedef __attribute__((ext_vector_type(8))) short short8;
typedef __attribute__((ext_vector_type(4))) float f32x4;

static __device__ __forceinline__ short f2bf(float x) {
    return __builtin_bit_cast(short, __float2bfloat16(x));   // HW v_cvt, RTNE
}
static __device__ __forceinline__ float bf2f(unsigned short s) {
    unsigned int u = ((unsigned int)s) << 16;
    return __builtin_bit_cast(float, u);
}

__device__ __forceinline__ void gl_lds16(const void* g, void* l) {
    __builtin_amdgcn_global_load_lds(
        (const __attribute__((address_space(1))) unsigned int*)g,
        (__attribute__((address_space(3))) unsigned int*)l, 16, 0, 0);
}

// ---------------------------------------------------------------------------
// Pack w1 (fp32 [8][1024][32]) -> MFMA B-frag order bf16:
//   w1p[((ks*16+cf)*64+lane)*8+r]; col=cf*16+(lane&15) (=h*32+e),
//   k=ks*32+(lane>>4)*8+r (=d)
__global__ void prep_w1(const float* __restrict__ w1, short* __restrict__ w1p) {
    int tid = blockIdx.x * 256 + threadIdx.x;   // 32768 threads
    int lane = tid & 63;
    int fragid = tid >> 6;
    int cf = fragid & 15, ks = fragid >> 4;
    int col = cf * 16 + (lane & 15);
    int h = col >> 5, e = col & 31;
    int d0 = ks * 32 + (lane >> 4) * 8;
    short8 v;
#pragma unroll
    for (int r = 0; r < 8; ++r)
        v[r] = f2bf(w1[((size_t)h * D_ + (d0 + r)) * 32 + e]);
    *(short8*)(w1p + (size_t)tid * 8) = v;
}

// Pack w2 (fp32 [8][32][128]) -> B-frag order bf16:
//   w2p[((h*8+cf2)*64+lane)*8+r]; col=o=cf2*16+(lane&15), k=e=(lane>>4)*8+r
__global__ void prep_w2(const float* __restrict__ w2, short* __restrict__ w2p) {
    int tid = blockIdx.x * 256 + threadIdx.x;   // 4096 threads
    int lane = tid & 63;
    int fragid = tid >> 6;
    int cf2 = fragid & 7, h = fragid >> 3;
    int o = cf2 * 16 + (lane & 15);
    int e0 = (lane >> 4) * 8;
    short8 v;
#pragma unroll
    for (int r = 0; r < 8; ++r)
        v[r] = f2bf(w2[((size_t)h * 32 + (e0 + r)) * 128 + o]);
    *(short8*)(w2p + (size_t)tid * 8) = v;
}

// ---------------------------------------------------------------------------
// gemm1: hact[m][0..256) = gelu(feat @ w1 + b1), bf16 row-major.
// STREAMER STRUCTURE (gemm2w-style): zero LDS in main loop, zero
// __syncthreads in the kernel, massive grid, free-running waves.
// Grid 1024 x 256 thr (4 waves, 2x2). Wave (wr,wc) = rows wr*32+[0,32) x
// cols wc*128+[0,128). A direct from feat (x2 dup = 512 MB, L3/HBM);
// B direct from w1p (L2-resident 512 KB, x2 dup = 1 GB L2). Per wave per
// kstep: 4 A-loads + 8 B-loads + 16 MFMA. acc 16 frags = 64 AGPR;
// ~90 VGPR -> ~3 waves/SIMD = 12 independent waves/CU hiding latency.
__global__ __launch_bounds__(256) void gemm1(
        const float* __restrict__ feat,
        const short* __restrict__ w1p,
        const float* __restrict__ b1,
        short* __restrict__ hact)
{
    __shared__ short hstage[4][32][136];   // per-wave private; epilogue only

    const int tid = threadIdx.x;
    const int wv = tid >> 6;
    const int lane = tid & 63;
    const int lr = lane & 15;
    const int lg = lane >> 4;
    const int wr = wv >> 1, wc = wv & 1;
    const size_t m0 = (size_t)blockIdx.x * 64;

    const float* A0 = feat + (m0 + (size_t)(wr * 32 + lr)) * D_;
    const float* A1 = feat + (m0 + (size_t)(wr * 32 + 16 + lr)) * D_;
    const short8* Bp = (const short8*)w1p;   // frag idx: (ks*16+cf)*64+lane

    const f32x4 vzero = {0.f, 0.f, 0.f, 0.f};
    f32x4 acc[2][8];
#pragma unroll
    for (int i = 0; i < 2; ++i)
#pragma unroll
        for (int j = 0; j < 8; ++j) acc[i][j] = vzero;

    // A prefetch (named regs, static indexing)
    f32x4 p0, p1, p2, p3;
    {
        const int o = lg * 8;
        p0 = *(const f32x4*)(A0 + o); p1 = *(const f32x4*)(A0 + o + 4);
        p2 = *(const f32x4*)(A1 + o); p3 = *(const f32x4*)(A1 + o + 4);
    }

    for (int ks = 0; ks < 32; ++ks) {
        short8 af0, af1;
        af0[0] = f2bf(p0.x); af0[1] = f2bf(p0.y); af0[2] = f2bf(p0.z); af0[3] = f2bf(p0.w);
        af0[4] = f2bf(p1.x); af0[5] = f2bf(p1.y); af0[6] = f2bf(p1.z); af0[7] = f2bf(p1.w);
        af1[0] = f2bf(p2.x); af1[1] = f2bf(p2.y); af1[2] = f2bf(p2.z); af1[3] = f2bf(p2.w);
        af1[4] = f2bf(p3.x); af1[5] = f2bf(p3.y); af1[6] = f2bf(p3.z); af1[7] = f2bf(p3.w);
        if (ks < 31) {
            const int o = (ks + 1) * 32 + lg * 8;
            p0 = *(const f32x4*)(A0 + o); p1 = *(const f32x4*)(A0 + o + 4);
            p2 = *(const f32x4*)(A1 + o); p3 = *(const f32x4*)(A1 + o + 4);
        }
        const short8* Bk = Bp + (size_t)ks * 1024 + (wc * 8) * 64 + lane;
#pragma unroll
        for (int j = 0; j < 8; ++j) {
            short8 b = Bk[j * 64];               // 1KB coalesced, L2-hit
            acc[0][j] = __builtin_amdgcn_mfma_f32_16x16x32_bf16(af0, b, acc[0][j], 0, 0, 0);
            acc[1][j] = __builtin_amdgcn_mfma_f32_16x16x32_bf16(af1, b, acc[1][j], 0, 0, 0);
        }
    }

    // epilogue: +b1, exact-erf gelu -> per-wave LDS slice -> coalesced store.
    // C/D frag layout: col = lane&15, row = (lane>>4)*4 + r.
#pragma unroll
    for (int cf = 0; cf < 8; ++cf) {
        const int col = wc * 128 + cf * 16 + lr;
        const float bias = b1[col];
#pragma unroll
        for (int a = 0; a < 2; ++a)
#pragma unroll
        for (int r = 0; r < 4; ++r) {
            const int row = a * 16 + lg * 4 + r;       // 0..31 within wave rows
            float x = acc[a][cf][r] + bias;
            float g = 0.5f * x * (1.0f + erff(x * 0.70710678118654752f));
            hstage[wv][row][cf * 16 + lr] = f2bf(g);
        }
    }
    // intra-wave LDS readback (lgkmcnt-ordered; no barrier needed)
#pragma unroll
    for (int it = 0; it < 8; ++it) {
        const int idx = it * 64 + lane;
        const int row = idx >> 4;           // 0..31
        const int c8 = idx & 15;            // 16 chunks of 8 shorts (128 cols)
        short8 v = *(const short8*)(&hstage[wv][row][c8 * 8]);
        *(short8*)(hact + (m0 + (size_t)(wr * 32 + row)) * 256 + wc * 128 + c8 * 8) = v;
    }
}

// ---------------------------------------------------------------------------
// gemm2w: per 16-row tile: logits = hact @ w2 + b2 ; E = exp(logits) ;
// partials pnum/pden[tile][col] = sum over 16 rows of {feat*E, E}.
// Block 256 thr; wave wv handles heads {2wv, 2wv+1} (logit cols wv*256..+256).
__global__ __launch_bounds__(256) void gemm2w(
        const short* __restrict__ hact,
        const float* __restrict__ feat,
        const short* __restrict__ w2p,
        const float* __restrict__ b2,
        float* __restrict__ pnum,
        float* __restrict__ pden)
{
    __shared__ __align__(16) char lds[41216];
    short* hstage = (short*)lds;                         // [16][256] linear, 8 KB
    unsigned short* Est = (unsigned short*)(lds + 8192); // [16][1032] bf16

    const int tid = threadIdx.x;
    const int wv = tid >> 6;
    const int lane = tid & 63;
    const int lr = lane & 15;
    const int lg = lane >> 4;
    const size_t m0 = (size_t)blockIdx.x * 16;

    // stage 16x256 bf16 hact tile (linear: matches gl_lds16 lane order)
#pragma unroll
    for (int j = 0; j < 2; ++j)
        gl_lds16(hact + m0 * 256 + (size_t)(j * 256 + tid) * 8,
                 hstage + (j * 256 + wv * 64) * 8);

    float bias2[16];
#pragma unroll
    for (int cf = 0; cf < 16; ++cf)
        bias2[cf] = b2[(2 * wv + (cf >> 3)) * 128 + (cf & 7) * 16 + lr];

    __syncthreads();

    // GEMM2 (K=32) + exp -> Est
    short8 ah0 = *(const short8*)(hstage + lr * 256 + (2 * wv + 0) * 32 + lg * 8);
    short8 ah1 = *(const short8*)(hstage + lr * 256 + (2 * wv + 1) * 32 + lg * 8);
    const f32x4 vzero = {0.f, 0.f, 0.f, 0.f};
#pragma unroll
    for (int cf = 0; cf < 16; ++cf) {
        const int h = 2 * wv + (cf >> 3);
        short8 bw = *(const short8*)(w2p + ((size_t)(h * 8 + (cf & 7)) * 64 + lane) * 8);
        f32x4 c = vzero;
        c = __builtin_amdgcn_mfma_f32_16x16x32_bf16((cf < 8) ? ah0 : ah1, bw, c, 0, 0, 0);
        const int colL = wv * 256 + (cf >> 3) * 128 + (cf & 7) * 16 + lr;
#pragma unroll
        for (int r = 0; r < 4; ++r) {
            float e = __expf(c[r] + bias2[cf]);   // logits tiny: no max-sub needed
            Est[(lg * 4 + r) * 1032 + colL] = (unsigned short)f2bf(e);
        }
    }
    __syncthreads();

    // weighting: coalesced f32x4 feat read, E from LDS
    const int c0 = tid * 4;
    f32x4 nacc = vzero, dacc = vzero;
    const float* fb = feat + m0 * D_ + c0;
#pragma unroll
    for (int row = 0; row < 16; ++row) {
        f32x4 fv = *(const f32x4*)(fb + (size_t)row * D_);
        unsigned long long ev = *(const unsigned long long*)(Est + row * 1032 + c0);
        f32x4 e;
        e.x = bf2f((unsigned short)(ev));
        e.y = bf2f((unsigned short)(ev >> 16));
        e.z = bf2f((unsigned short)(ev >> 32));
        e.w = bf2f((unsigned short)(ev >> 48));
        dacc += e;
        nacc += fv * e;
    }
    const size_t pb = (size_t)blockIdx.x * 1024 + c0;
    *(f32x4*)(pnum + pb) = nacc;
    *(f32x4*)(pden + pb) = dacc;
}

// ---------------------------------------------------------------------------
// out[b,d] = sum_{j<128} pnum[(b*128+j)*1024+d] / sum_j pden[...]
__global__ __launch_bounds__(256) void finalize3(
        const float* __restrict__ pnum,
        const float* __restrict__ pden,
        float* __restrict__ out)
{
    const int idx = blockIdx.x * 256 + threadIdx.x;   // 32768 = 32*1024
    const int b = idx >> 10;
    const int d = idx & 1023;
    const size_t base = (size_t)b * 128 * 1024 + d;
    float n = 0.f, dn = 0.f;
    for (int j = 0; j < 128; ++j) {
        n  += pnum[base + (size_t)j * 1024];
        dn += pden[base + (size_t)j * 1024];
    }
    out[idx] = n / dn;
}

// ---------------------------------------------------------------------------
extern "C" void kernel_launch(void* const* d_in, const int* in_sizes, int n_in,
                              void* d_out, int out_size, void* d_ws, size_t ws_size,
                              hipStream_t stream) {
    (void)in_sizes; (void)n_in; (void)out_size; (void)ws_size;
    const float* feat = (const float*)d_in[0];
    const float* w1   = (const float*)d_in[1];
    const float* b1   = (const float*)d_in[2];
    const float* w2   = (const float*)d_in[3];
    const float* b2   = (const float*)d_in[4];
    float* out = (float*)d_out;

    char* ws = (char*)d_ws;
    short* hact = (short*)ws;                              // 32 MiB (65536*256 bf16)
    float* pnum = (float*)(ws + (32ull << 20));            // 16 MiB (4096*1024 f32)
    float* pden = (float*)(ws + (48ull << 20));            // 16 MiB
    short* w1p  = (short*)(ws + (64ull << 20));            // 512 KiB
    short* w2p  = (short*)(ws + (64ull << 20) + (512ull << 10));  // 64 KiB

    prep_w1<<<128, 256, 0, stream>>>(w1, w1p);
    prep_w2<<<16, 256, 0, stream>>>(w2, w2p);
    gemm1<<<1024, 256, 0, stream>>>(feat, w1p, b1, hact);
    gemm2w<<<4096, 256, 0, stream>>>(hact, feat, w2p, b2, pnum, pden);
    finalize3<<<128, 256, 0, stream>>>(pnum, pden, out);
}

// Round 9
// 187.616 us; speedup vs baseline: 1.5406x; 1.1578x over previous
//
#include <hip/hip_runtime.h>
#include <hip/hip_bf16.h>
#include <math.h>

// B=32, S=2048, D=1024, H=8, D_HEAD=32, D_HEAD_OUT=128, M=65536
#define S_  2048
#define D_  1024

typedef __attribute__((ext_vector_type(8))) short short8;
typedef __attribute__((ext_vector_type(4))) float f32x4;

static __device__ __forceinline__ short f2bf(float x) {
    return __builtin_bit_cast(short, __float2bfloat16(x));   // HW v_cvt, RTNE
}
static __device__ __forceinline__ float bf2f(unsigned short s) {
    unsigned int u = ((unsigned int)s) << 16;
    return __builtin_bit_cast(float, u);
}

__device__ __forceinline__ void gl_lds16(const void* g, void* l) {
    __builtin_amdgcn_global_load_lds(
        (const __attribute__((address_space(1))) unsigned int*)g,
        (__attribute__((address_space(3))) unsigned int*)l, 16, 0, 0);
}

// ---------------------------------------------------------------------------
// Pack w1 (fp32 [8][1024][32]) -> MFMA B-frag order bf16:
//   w1p[((ks*16+cf)*64+lane)*8+r]; col=cf*16+(lane&15) (=h*32+e),
//   k=ks*32+(lane>>4)*8+r (=d)
__global__ void prep_w1(const float* __restrict__ w1, short* __restrict__ w1p) {
    int tid = blockIdx.x * 256 + threadIdx.x;   // 32768 threads
    int lane = tid & 63;
    int fragid = tid >> 6;
    int cf = fragid & 15, ks = fragid >> 4;
    int col = cf * 16 + (lane & 15);
    int h = col >> 5, e = col & 31;
    int d0 = ks * 32 + (lane >> 4) * 8;
    short8 v;
#pragma unroll
    for (int r = 0; r < 8; ++r)
        v[r] = f2bf(w1[((size_t)h * D_ + (d0 + r)) * 32 + e]);
    *(short8*)(w1p + (size_t)tid * 8) = v;
}

// Pack w2 (fp32 [8][32][128]) -> B-frag order bf16:
//   w2p[((h*8+cf2)*64+lane)*8+r]; col=o=cf2*16+(lane&15), k=e=(lane>>4)*8+r
__global__ void prep_w2(const float* __restrict__ w2, short* __restrict__ w2p) {
    int tid = blockIdx.x * 256 + threadIdx.x;   // 4096 threads
    int lane = tid & 63;
    int fragid = tid >> 6;
    int cf2 = fragid & 7, h = fragid >> 3;
    int o = cf2 * 16 + (lane & 15);
    int e0 = (lane >> 4) * 8;
    short8 v;
#pragma unroll
    for (int r = 0; r < 8; ++r)
        v[r] = f2bf(w2[((size_t)h * 32 + (e0 + r)) * 128 + o]);
    *(short8*)(w2p + (size_t)tid * 8) = v;
}

// ---------------------------------------------------------------------------
// gemm1: hact[m][0..256) = gelu(feat @ w1 + b1), bf16 row-major.
// BM=128, BN=128, BK=32. Grid 1024 (512 mblk x 2 nblk), 256 thr (4 waves 2x2).
// Wave (wr,wc2): rows wr*64+[0,64), cols wc2*64+[0,64); acc 4x4 f32x4 = 64 AGPR.
// T3/T4 pipeline: 3 LDS stage buffers, tile k+2 staged after barrier,
// s_waitcnt vmcnt(6) (counted, never 0 in main loop) -> 2 iterations of
// latency slack per tile. A kept fp32 in LDS with XOR swizzle
// (byte ^= (row&7)<<4), cvt->bf16 at frag build. B from frag-packed w1p.
// Per kstep: stage A 16KB (4 gl_lds/thr) + B 8KB (2 gl_lds/thr); 12 ds_reads,
// 16 MFMA per wave. LDS 72KB -> 2 blocks/CU.
__global__ __launch_bounds__(256) void gemm1(
        const float* __restrict__ feat,
        const short* __restrict__ w1p,
        const float* __restrict__ b1,
        short* __restrict__ hact)
{
    __shared__ __align__(16) char lds[73728];
    char* Abuf = lds;                    // 3 x 16384 B (128 rows x 128 B)
    char* Bbuf = lds + 49152;            // 3 x 8192 B
    short* hstage = (short*)lds;         // [64][136] bf16 (epilogue reuse)

    const int tid = threadIdx.x;
    const int wv = tid >> 6;
    const int lane = tid & 63;
    const int lr = lane & 15;
    const int lg = lane >> 4;
    const int wr = wv >> 1, wc2 = wv & 1;
    const int mblk = blockIdx.x >> 1, nblk = blockIdx.x & 1;
    const size_t m0 = (size_t)mblk * 128;

    // ---- A staging: 1024 slots x 16B per kstep. slot s: row=s>>3, seg=s&7.
    // LDS byte row*128+seg*16 holds global k-bytes (seg*16)^((row&7)<<4).
    // Thread t handles slots t + q*256 (q=0..3): seg = t&7 (const), row = (t>>3)+q*32.
    const int segA = tid & 7;
    const int rA = tid >> 3;
    const int swbA = (segA * 16) ^ ((rA & 7) << 4);      // (row&7)==(rA&7) for all q
    const float* gA = feat + (m0 + rA) * D_ + (swbA >> 2);
    // ---- B staging: 512 slots x 16B; slot s -> w1p shorts (ks*16+nblk*8)*512 + s*8
    const short* gB = w1p + (size_t)(nblk * 8) * 512 + tid * 8;

    auto stageA = [&](int buf, int ks) {
        const float* g = gA + ks * 32;
        char* d = Abuf + buf * 16384 + tid * 16;
#pragma unroll
        for (int q = 0; q < 4; ++q)
            gl_lds16(g + (size_t)q * 32 * D_, d + q * 4096);
    };
    auto stageB = [&](int buf, int ks) {
        const short* g = gB + ks * 8192;
        char* d = Bbuf + buf * 8192 + tid * 16;
        gl_lds16(g, d);
        gl_lds16(g + 2048, d + 4096);
    };

    const f32x4 vzero = {0.f, 0.f, 0.f, 0.f};
    f32x4 acc[4][4];
#pragma unroll
    for (int i = 0; i < 4; ++i)
#pragma unroll
        for (int j = 0; j < 4; ++j) acc[i][j] = vzero;

    const int axor = (lr & 7) << 4;

    auto compute = [&](int bi) {
        const char* Ab = Abuf + bi * 16384;
        const char* Bb = Bbuf + bi * 8192;
        short8 bfr0 = *(const short8*)(Bb + ((wc2 * 4 + 0) * 64 + lane) * 16);
        short8 bfr1 = *(const short8*)(Bb + ((wc2 * 4 + 1) * 64 + lane) * 16);
        short8 bfr2 = *(const short8*)(Bb + ((wc2 * 4 + 2) * 64 + lane) * 16);
        short8 bfr3 = *(const short8*)(Bb + ((wc2 * 4 + 3) * 64 + lane) * 16);
#pragma unroll
        for (int i = 0; i < 4; ++i) {
            const int row = wr * 64 + i * 16 + lr;
            f32x4 alo = *(const f32x4*)(Ab + row * 128 + ((lg * 32) ^ axor));
            f32x4 ahi = *(const f32x4*)(Ab + row * 128 + ((lg * 32 + 16) ^ axor));
            short8 af;
            af[0] = f2bf(alo.x); af[1] = f2bf(alo.y);
            af[2] = f2bf(alo.z); af[3] = f2bf(alo.w);
            af[4] = f2bf(ahi.x); af[5] = f2bf(ahi.y);
            af[6] = f2bf(ahi.z); af[7] = f2bf(ahi.w);
            acc[i][0] = __builtin_amdgcn_mfma_f32_16x16x32_bf16(af, bfr0, acc[i][0], 0, 0, 0);
            acc[i][1] = __builtin_amdgcn_mfma_f32_16x16x32_bf16(af, bfr1, acc[i][1], 0, 0, 0);
            acc[i][2] = __builtin_amdgcn_mfma_f32_16x16x32_bf16(af, bfr2, acc[i][2], 0, 0, 0);
            acc[i][3] = __builtin_amdgcn_mfma_f32_16x16x32_bf16(af, bfr3, acc[i][3], 0, 0, 0);
        }
    };

    // prologue: tiles 0,1 in flight (12 outstanding gl_lds per thread)
    stageA(0, 0); stageB(0, 0);
    stageA(1, 1); stageB(1, 1);

    int cur = 0;
    for (int ks = 0; ks < 30; ++ks) {
        asm volatile("s_waitcnt vmcnt(6)" ::: "memory");   // tile ks landed; ks+1 in flight
        __builtin_amdgcn_sched_barrier(0);
        __builtin_amdgcn_s_barrier();                       // all waves see tile ks in LDS
        int sb = cur + 2; if (sb >= 3) sb -= 3;
        stageA(sb, ks + 2); stageB(sb, ks + 2);             // issue tile ks+2
        compute(cur);
        cur = (cur == 2) ? 0 : cur + 1;
    }
    // ks=30: tile 31 still in flight (6 outstanding)
    asm volatile("s_waitcnt vmcnt(6)" ::: "memory");
    __builtin_amdgcn_sched_barrier(0);
    __builtin_amdgcn_s_barrier();
    compute(cur);
    cur = (cur == 2) ? 0 : cur + 1;
    // ks=31: full drain
    asm volatile("s_waitcnt vmcnt(0)" ::: "memory");
    __builtin_amdgcn_sched_barrier(0);
    __builtin_amdgcn_s_barrier();
    compute(cur);
    __syncthreads();    // all LDS reads done -> hstage reuse safe

    // ---- epilogue: +b1, exact-erf gelu; 2 passes of 64 rows via LDS ----
    // C/D frag layout: col = lane&15, row = (lane>>4)*4 + r.
#pragma unroll
    for (int p = 0; p < 2; ++p) {
        if (wr == p) {
#pragma unroll
            for (int j = 0; j < 4; ++j) {
                const int col = wc2 * 64 + j * 16 + lr;
                const float bias = b1[nblk * 128 + col];
#pragma unroll
                for (int i = 0; i < 4; ++i)
#pragma unroll
                for (int r = 0; r < 4; ++r) {
                    const int lrow = i * 16 + lg * 4 + r;
                    float x = acc[i][j][r] + bias;
                    float g = 0.5f * x * (1.0f + erff(x * 0.70710678118654752f));
                    hstage[lrow * 136 + col] = f2bf(g);
                }
            }
        }
        __syncthreads();
#pragma unroll
        for (int it = 0; it < 4; ++it) {
            const int idx = it * 256 + tid;
            const int row = idx >> 4;          // 64 rows
            const int c8 = idx & 15;           // 16 chunks of 8 bf16
            short8 v = *(const short8*)(hstage + row * 136 + c8 * 8);
            *(short8*)(hact + (m0 + (size_t)(p * 64 + row)) * 256 + nblk * 128 + c8 * 8) = v;
        }
        __syncthreads();
    }
}

// ---------------------------------------------------------------------------
// gemm2w: per 16-row tile: logits = hact @ w2 + b2 ; E = exp(logits) ;
// partials pnum/pden[tile][col] = sum over 16 rows of {feat*E, E}.
// Block 256 thr; wave wv handles heads {2wv, 2wv+1} (logit cols wv*256..+256).
__global__ __launch_bounds__(256) void gemm2w(
        const short* __restrict__ hact,
        const float* __restrict__ feat,
        const short* __restrict__ w2p,
        const float* __restrict__ b2,
        float* __restrict__ pnum,
        float* __restrict__ pden)
{
    __shared__ __align__(16) char lds[41216];
    short* hstage = (short*)lds;                         // [16][256] linear, 8 KB
    unsigned short* Est = (unsigned short*)(lds + 8192); // [16][1032] bf16

    const int tid = threadIdx.x;
    const int wv = tid >> 6;
    const int lane = tid & 63;
    const int lr = lane & 15;
    const int lg = lane >> 4;
    const size_t m0 = (size_t)blockIdx.x * 16;

    // stage 16x256 bf16 hact tile (linear: matches gl_lds16 lane order)
#pragma unroll
    for (int j = 0; j < 2; ++j)
        gl_lds16(hact + m0 * 256 + (size_t)(j * 256 + tid) * 8,
                 hstage + (j * 256 + wv * 64) * 8);

    float bias2[16];
#pragma unroll
    for (int cf = 0; cf < 16; ++cf)
        bias2[cf] = b2[(2 * wv + (cf >> 3)) * 128 + (cf & 7) * 16 + lr];

    __syncthreads();

    // GEMM2 (K=32) + exp -> Est
    short8 ah0 = *(const short8*)(hstage + lr * 256 + (2 * wv + 0) * 32 + lg * 8);
    short8 ah1 = *(const short8*)(hstage + lr * 256 + (2 * wv + 1) * 32 + lg * 8);
    const f32x4 vzero = {0.f, 0.f, 0.f, 0.f};
#pragma unroll
    for (int cf = 0; cf < 16; ++cf) {
        const int h = 2 * wv + (cf >> 3);
        short8 bw = *(const short8*)(w2p + ((size_t)(h * 8 + (cf & 7)) * 64 + lane) * 8);
        f32x4 c = vzero;
        c = __builtin_amdgcn_mfma_f32_16x16x32_bf16((cf < 8) ? ah0 : ah1, bw, c, 0, 0, 0);
        const int colL = wv * 256 + (cf >> 3) * 128 + (cf & 7) * 16 + lr;
#pragma unroll
        for (int r = 0; r < 4; ++r) {
            float e = __expf(c[r] + bias2[cf]);   // logits tiny: no max-sub needed
            Est[(lg * 4 + r) * 1032 + colL] = (unsigned short)f2bf(e);
        }
    }
    __syncthreads();

    // weighting: coalesced f32x4 feat read, E from LDS
    const int c0 = tid * 4;
    f32x4 nacc = vzero, dacc = vzero;
    const float* fb = feat + m0 * D_ + c0;
#pragma unroll
    for (int row = 0; row < 16; ++row) {
        f32x4 fv = *(const f32x4*)(fb + (size_t)row * D_);
        unsigned long long ev = *(const unsigned long long*)(Est + row * 1032 + c0);
        f32x4 e;
        e.x = bf2f((unsigned short)(ev));
        e.y = bf2f((unsigned short)(ev >> 16));
        e.z = bf2f((unsigned short)(ev >> 32));
        e.w = bf2f((unsigned short)(ev >> 48));
        dacc += e;
        nacc += fv * e;
    }
    const size_t pb = (size_t)blockIdx.x * 1024 + c0;
    *(f32x4*)(pnum + pb) = nacc;
    *(f32x4*)(pden + pb) = dacc;
}

// ---------------------------------------------------------------------------
// out[b,d] = sum_{j<128} pnum[(b*128+j)*1024+d] / sum_j pden[...]
__global__ __launch_bounds__(256) void finalize3(
        const float* __restrict__ pnum,
        const float* __restrict__ pden,
        float* __restrict__ out)
{
    const int idx = blockIdx.x * 256 + threadIdx.x;   // 32768 = 32*1024
    const int b = idx >> 10;
    const int d = idx & 1023;
    const size_t base = (size_t)b * 128 * 1024 + d;
    float n = 0.f, dn = 0.f;
    for (int j = 0; j < 128; ++j) {
        n  += pnum[base + (size_t)j * 1024];
        dn += pden[base + (size_t)j * 1024];
    }
    out[idx] = n / dn;
}

// ---------------------------------------------------------------------------
extern "C" void kernel_launch(void* const* d_in, const int* in_sizes, int n_in,
                              void* d_out, int out_size, void* d_ws, size_t ws_size,
                              hipStream_t stream) {
    (void)in_sizes; (void)n_in; (void)out_size; (void)ws_size;
    const float* feat = (const float*)d_in[0];
    const float* w1   = (const float*)d_in[1];
    const float* b1   = (const float*)d_in[2];
    const float* w2   = (const float*)d_in[3];
    const float* b2   = (const float*)d_in[4];
    float* out = (float*)d_out;

    char* ws = (char*)d_ws;
    short* hact = (short*)ws;                              // 32 MiB (65536*256 bf16)
    float* pnum = (float*)(ws + (32ull << 20));            // 16 MiB (4096*1024 f32)
    float* pden = (float*)(ws + (48ull << 20));            // 16 MiB
    short* w1p  = (short*)(ws + (64ull << 20));            // 512 KiB
    short* w2p  = (short*)(ws + (64ull << 20) + (512ull << 10));  // 64 KiB

    prep_w1<<<128, 256, 0, stream>>>(w1, w1p);
    prep_w2<<<16, 256, 0, stream>>>(w2, w2p);
    gemm1<<<1024, 256, 0, stream>>>(feat, w1p, b1, hact);
    gemm2w<<<4096, 256, 0, stream>>>(hact, feat, w2p, b2, pnum, pden);
    finalize3<<<128, 256, 0, stream>>>(pnum, pden, out);
}